// Round 19
// baseline (182.231 us; speedup 1.0000x reference)
//
#include <hip/hip_runtime.h>

#define ROWS_TOTAL 131072
#define XST 224             // g_xb row stride in bf16 elements (448 B, zero-padded)

typedef float f32x4 __attribute__((ext_vector_type(4)));
typedef short s16x8 __attribute__((ext_vector_type(8)));

// W fragment-linear, per 16-col n-frag:
//   byte = (n*7 + kk)*1024 + col16*64 + ks*16 + e*2   (zero-padded k>=196)
__device__ unsigned short g_Wb4[49 * 7 * 16 * 32];          // 351 KB
// x patchified, bf16, row stride 224 ushorts (zero-padded k = 196..223)
__device__ unsigned short g_xb[(size_t)ROWS_TOTAL * XST];   // 58.7 MB

__device__ __forceinline__ unsigned short f2bf(float f) {
    unsigned int u = __builtin_bit_cast(unsigned int, f);
    u += 0x7fffu + ((u >> 16) & 1u);        // round-to-nearest-even
    return (unsigned short)(u >> 16);
}

__global__ void prep_w(const float* __restrict__ W) {
    int t = blockIdx.x * 256 + threadIdx.x;   // 784 cols * 56 k-quads
    if (t >= 784 * 56) return;
    int col = t / 56;
    int k0  = (t - col * 56) * 4;
    uint2 pk;
    if (k0 < 196) {
        f32x4 d = *(const f32x4*)(W + col * 196 + k0);
        pk.x = (unsigned int)f2bf(d[0]) | ((unsigned int)f2bf(d[1]) << 16);
        pk.y = (unsigned int)f2bf(d[2]) | ((unsigned int)f2bf(d[3]) << 16);
    } else {
        pk.x = 0u; pk.y = 0u;
    }
    int ng = col >> 4, col16 = col & 15;
    int kk = k0 >> 5, rem = k0 & 31, ks = rem >> 3, e0 = rem & 7;
    size_t di = (size_t)((ng * 7 + kk) * 16 + col16) * 32 + ks * 8 + e0;
    *(uint2*)(g_Wb4 + di) = pk;
}

// patchify: x[32768,28,28] fp32 -> g_xb[131072][224] bf16 (zero-padded)
__global__ void prep_x(const float* __restrict__ x) {
    const int NV = ROWS_TOTAL / 4 * 784 / 4;            // 6,422,528 float4s
    const f32x4* xv = (const f32x4*)x;
    for (int v = blockIdx.x * 256 + threadIdx.x; v < NV; v += gridDim.x * 256) {
        f32x4 d = xv[v];
        int F   = v * 4;
        int img = F / 784;
        int rem = F - img * 784;
        int h   = rem / 28;
        int w0  = rem - h * 28;          // in {0,4,...,24}
        int ph  = h / 14;
        int r   = h - ph * 14;
        int rowb = img * 4 + ph * 2;
        #pragma unroll
        for (int p = 0; p < 2; ++p) {
            int w  = w0 + 2 * p;         // even => bf16 pair stays inside one patch
            int pw = (w >= 14) ? 1 : 0;
            int c  = w - pw * 14;
            int row = rowb + pw;
            unsigned int pack = (unsigned int)f2bf(d[2 * p]) |
                                ((unsigned int)f2bf(d[2 * p + 1]) << 16);
            *(unsigned int*)((char*)g_xb + (size_t)row * (XST * 2) + (r * 14 + c) * 2) = pack;
        }
    }
    // zero pad k = 196..223 for every row
    for (int t = blockIdx.x * 256 + threadIdx.x; t < ROWS_TOTAL * 7; t += gridDim.x * 256) {
        int row = t / 7;
        int j   = t - row * 7;
        *(uint2*)((char*)g_xb + (size_t)row * (XST * 2) + 392 + j * 8) = (uint2){0u, 0u};
    }
}

__device__ __forceinline__ void gload_lds16(void* lds, const void* g) {
    __builtin_amdgcn_global_load_lds(
        (const __attribute__((address_space(1))) unsigned int*)g,
        (__attribute__((address_space(3))) unsigned int*)lds, 16, 0, 0);
}

// Block: 256 out rows x 112 out cols; 8 waves, wave = 32 rows (m0 then m1).
// W group (49 KiB) staged once per block via linear DMA. launch_bounds(512,6)
// -> 3 co-resident blocks/CU (147 KiB LDS, 24 waves): barrier drains and
// store bursts of one block hide under the other two blocks' compute.
// MFMA loops n-OUTER: each acc[n] stores immediately after its 7 MFMAs ->
// 14 store points spread across the compute phase (smooth write stream).
// All output stores nontemporal. Same-XCD sibling swizzle as R18.
__global__ __launch_bounds__(512, 6)
void patch_linear_mfma(const float* __restrict__ blin,
                       float* __restrict__ out) {
    __shared__ __align__(16) char sW[49 * 1024];   // [nn][kk][1 KiB]

    const int tid  = threadIdx.x;
    const int l    = tid & 63;
    const int wv   = tid >> 6;          // 0..7
    const int lrow = l & 15;
    const int lk   = l >> 4;

    const int bid = blockIdx.x;         // 0..3583
    const int xcd = bid & 7;
    const int t   = bid >> 3;           // 0..447
    const int q   = t / 7;              // 0..63
    const int cg  = t - q * 7;          // 0..6
    const int rg  = q * 8 + xcd;        // 0..511 (256-row group)

    // ---- stage W group: 49 x 1 KiB linear async DMA ----
    const char* wsrc = (const char*)g_Wb4 + (size_t)cg * 50176 + l * 16;
    #pragma unroll
    for (int c = 0; c < 7; ++c) {
        int ch = wv + c * 8;
        if (ch < 49) gload_lds16(sW + ch * 1024, wsrc + ch * 1024);
    }

    // ---- xf (m=0 half) -> registers; flies under the DMA ----
    const size_t row0 = (size_t)rg * 256 + wv * 32 + lrow;
    const char* xb = (const char*)g_xb + row0 * 448 + lk * 16;
    s16x8 xf0[7];
    #pragma unroll
    for (int kk = 0; kk < 7; ++kk)
        xf0[kk] = *(const s16x8*)(xb + kk * 64);

    // ---- bias ----
    f32x4 bias[7];
    #pragma unroll
    for (int n = 0; n < 7; ++n)
        bias[n] = *(const f32x4*)(blin + cg * 112 + n * 16 + lk * 4);

    __syncthreads();   // drains DMA; the only barrier

    // issue m=1 xf loads immediately: they fly under the m0 MFMA phase
    s16x8 xf1[7];
    #pragma unroll
    for (int kk = 0; kk < 7; ++kk)
        xf1[kk] = *(const s16x8*)(xb + 16 * 448 + kk * 64);

    const char* wb = sW + lrow * 64 + lk * 16;
    float* orow0 = out + row0 * 784 + cg * 112 + lk * 4;
    float* orow1 = orow0 + 16 * 784;

    // ---- m0: n-outer; store each acc[n] as soon as it completes ----
    #pragma unroll
    for (int n = 0; n < 7; ++n) {
        f32x4 a = bias[n];
        #pragma unroll
        for (int kk = 0; kk < 7; ++kk) {
            s16x8 wf = *(const s16x8*)(wb + (n * 7 + kk) * 1024);
            a = __builtin_amdgcn_mfma_f32_16x16x32_bf16(wf, xf0[kk], a, 0, 0, 0);
        }
        __builtin_nontemporal_store(a, (f32x4*)(orow0 + n * 16));
    }

    // ---- m1: same, second 16-row half ----
    #pragma unroll
    for (int n = 0; n < 7; ++n) {
        f32x4 a = bias[n];
        #pragma unroll
        for (int kk = 0; kk < 7; ++kk) {
            s16x8 wf = *(const s16x8*)(wb + (n * 7 + kk) * 1024);
            a = __builtin_amdgcn_mfma_f32_16x16x32_bf16(wf, xf1[kk], a, 0, 0, 0);
        }
        __builtin_nontemporal_store(a, (f32x4*)(orow1 + n * 16));
    }
}

extern "C" void kernel_launch(void* const* d_in, const int* in_sizes, int n_in,
                              void* d_out, int out_size, void* d_ws, size_t ws_size,
                              hipStream_t stream) {
    const float* x    = (const float*)d_in[0];   // [32768,1,28,28]
    const float* Wlin = (const float*)d_in[1];   // [784,196]
    const float* blin = (const float*)d_in[2];   // [784]
    float* out = (float*)d_out;                  // [32768,4,784]

    prep_w<<<(784 * 56 + 255) / 256, 256, 0, stream>>>(Wlin);
    prep_x<<<4096, 256, 0, stream>>>(x);

    dim3 grid(512 * 7);                          // 3584 blocks, same-XCD siblings
    dim3 block(512);
    patch_linear_mfma<<<grid, block, 0, stream>>>(blin, out);
}

// Round 20
// 128.280 us; speedup vs baseline: 1.4206x; 1.4206x over previous
//
#include <hip/hip_runtime.h>

#define ROWS_TOTAL 131072
#define XST 224             // g_xb row stride in bf16 elements (448 B, zero-padded)

typedef float f32x4 __attribute__((ext_vector_type(4)));
typedef short s16x8 __attribute__((ext_vector_type(8)));

// W fragment-linear, per 16-col n-frag:
//   byte = (n*7 + kk)*1024 + col16*64 + ks*16 + e*2   (zero-padded k>=196)
__device__ unsigned short g_Wb4[49 * 7 * 16 * 32];          // 351 KB
// x patchified, bf16, row stride 224 ushorts (zero-padded k = 196..223)
__device__ unsigned short g_xb[(size_t)ROWS_TOTAL * XST];   // 58.7 MB

__device__ __forceinline__ unsigned short f2bf(float f) {
    unsigned int u = __builtin_bit_cast(unsigned int, f);
    u += 0x7fffu + ((u >> 16) & 1u);        // round-to-nearest-even
    return (unsigned short)(u >> 16);
}

__global__ void prep_w(const float* __restrict__ W) {
    int t = blockIdx.x * 256 + threadIdx.x;   // 784 cols * 56 k-quads
    if (t >= 784 * 56) return;
    int col = t / 56;
    int k0  = (t - col * 56) * 4;
    uint2 pk;
    if (k0 < 196) {
        f32x4 d = *(const f32x4*)(W + col * 196 + k0);
        pk.x = (unsigned int)f2bf(d[0]) | ((unsigned int)f2bf(d[1]) << 16);
        pk.y = (unsigned int)f2bf(d[2]) | ((unsigned int)f2bf(d[3]) << 16);
    } else {
        pk.x = 0u; pk.y = 0u;
    }
    int ng = col >> 4, col16 = col & 15;
    int kk = k0 >> 5, rem = k0 & 31, ks = rem >> 3, e0 = rem & 7;
    size_t di = (size_t)((ng * 7 + kk) * 16 + col16) * 32 + ks * 8 + e0;
    *(uint2*)(g_Wb4 + di) = pk;
}

// patchify: x[32768,28,28] fp32 -> g_xb[131072][224] bf16 (zero-padded)
__global__ void prep_x(const float* __restrict__ x) {
    const int NV = ROWS_TOTAL / 4 * 784 / 4;            // 6,422,528 float4s
    const f32x4* xv = (const f32x4*)x;
    for (int v = blockIdx.x * 256 + threadIdx.x; v < NV; v += gridDim.x * 256) {
        f32x4 d = xv[v];
        int F   = v * 4;
        int img = F / 784;
        int rem = F - img * 784;
        int h   = rem / 28;
        int w0  = rem - h * 28;          // in {0,4,...,24}
        int ph  = h / 14;
        int r   = h - ph * 14;
        int rowb = img * 4 + ph * 2;
        #pragma unroll
        for (int p = 0; p < 2; ++p) {
            int w  = w0 + 2 * p;         // even => bf16 pair stays inside one patch
            int pw = (w >= 14) ? 1 : 0;
            int c  = w - pw * 14;
            int row = rowb + pw;
            unsigned int pack = (unsigned int)f2bf(d[2 * p]) |
                                ((unsigned int)f2bf(d[2 * p + 1]) << 16);
            *(unsigned int*)((char*)g_xb + (size_t)row * (XST * 2) + (r * 14 + c) * 2) = pack;
        }
    }
    // zero pad k = 196..223 for every row
    for (int t = blockIdx.x * 256 + threadIdx.x; t < ROWS_TOTAL * 7; t += gridDim.x * 256) {
        int row = t / 7;
        int j   = t - row * 7;
        *(uint2*)((char*)g_xb + (size_t)row * (XST * 2) + 392 + j * 8) = (uint2){0u, 0u};
    }
}

__device__ __forceinline__ void gload_lds16(void* lds, const void* g) {
    __builtin_amdgcn_global_load_lds(
        (const __attribute__((address_space(1))) unsigned int*)g,
        (__attribute__((address_space(3))) unsigned int*)lds, 16, 0, 0);
}

// load 7 xf fragments (one 16-row half) into a named reg array
#define LDXF(XF, XBP) do {                                                      \
    _Pragma("unroll") for (int kk = 0; kk < 7; ++kk)                            \
        XF[kk] = *(const s16x8*)((XBP) + kk * 64);                              \
} while (0)

// one 16-row m-phase: acc init from blin (L1-hit), kk-outer MFMA, nt stores
#define MPHASE(XF, OROW) do {                                                   \
    f32x4 acc_[7];                                                              \
    _Pragma("unroll") for (int n = 0; n < 7; ++n)                               \
        acc_[n] = *(const f32x4*)(blin + cg * 112 + n * 16 + lk * 4);           \
    _Pragma("unroll") for (int kk = 0; kk < 7; ++kk)                            \
        _Pragma("unroll") for (int n = 0; n < 7; ++n) {                         \
            s16x8 wf_ = *(const s16x8*)(wb + (n * 7 + kk) * 1024);              \
            acc_[n] = __builtin_amdgcn_mfma_f32_16x16x32_bf16(                  \
                wf_, XF[kk], acc_[n], 0, 0, 0);                                 \
        }                                                                       \
    _Pragma("unroll") for (int n = 0; n < 7; ++n)                               \
        __builtin_nontemporal_store(acc_[n], (f32x4*)((OROW) + n * 16));        \
} while (0)

// Block: TWO 256-row tiles x 112 cols (512 rows total) with one sW staging and
// ONE barrier. 8 waves; wave = 32 rows per tile (m0,m1). Tile-2 xf loads are
// issued between tile-1 phases (fly under MFMA). W DMA: 1792 x 50 KB = 90 MB.
// nt stores; same-XCD sibling swizzle (rg512 = q*8 + xcd).
__global__ __launch_bounds__(512, 4)
void patch_linear_mfma(const float* __restrict__ blin,
                       float* __restrict__ out) {
    __shared__ __align__(16) char sW[49 * 1024];   // [nn][kk][1 KiB]

    const int tid  = threadIdx.x;
    const int l    = tid & 63;
    const int wv   = tid >> 6;          // 0..7
    const int lrow = l & 15;
    const int lk   = l >> 4;

    const int bid = blockIdx.x;         // 0..1791
    const int xcd = bid & 7;
    const int t   = bid >> 3;           // 0..223
    const int q   = t / 7;              // 0..31
    const int cg  = t - q * 7;          // 0..6
    const int rg  = q * 8 + xcd;        // 0..255 (512-row group)

    // ---- stage W group: 49 x 1 KiB linear async DMA ----
    const char* wsrc = (const char*)g_Wb4 + (size_t)cg * 50176 + l * 16;
    #pragma unroll
    for (int c = 0; c < 7; ++c) {
        int ch = wv + c * 8;
        if (ch < 49) gload_lds16(sW + ch * 1024, wsrc + ch * 1024);
    }

    // row bases: tile0 / tile1
    const size_t row0 = (size_t)rg * 512 + wv * 32 + lrow;
    const size_t row1 = row0 + 256;
    const char* xb0 = (const char*)g_xb + row0 * 448 + lk * 16;
    const char* xb1 = (const char*)g_xb + row1 * 448 + lk * 16;
    float* o00 = out + row0 * 784 + cg * 112 + lk * 4;   // t0 m0
    float* o01 = o00 + 16 * 784;                          // t0 m1
    float* o10 = out + row1 * 784 + cg * 112 + lk * 4;   // t1 m0
    float* o11 = o10 + 16 * 784;                          // t1 m1

    s16x8 xfa[7], xfb[7];
    LDXF(xfa, xb0);                     // t0 m0, flies under the DMA

    __syncthreads();                    // drains DMA; the only barrier

    const char* wb = sW + lrow * 64 + lk * 16;

    LDXF(xfb, xb0 + 16 * 448);          // t0 m1, flies under t0-m0 MFMAs
    MPHASE(xfa, o00);

    LDXF(xfa, xb1);                     // t1 m0, flies under t0-m1 MFMAs
    MPHASE(xfb, o01);

    LDXF(xfb, xb1 + 16 * 448);          // t1 m1, flies under t1-m0 MFMAs
    MPHASE(xfa, o10);

    MPHASE(xfb, o11);
}

extern "C" void kernel_launch(void* const* d_in, const int* in_sizes, int n_in,
                              void* d_out, int out_size, void* d_ws, size_t ws_size,
                              hipStream_t stream) {
    const float* x    = (const float*)d_in[0];   // [32768,1,28,28]
    const float* Wlin = (const float*)d_in[1];   // [784,196]
    const float* blin = (const float*)d_in[2];   // [784]
    float* out = (float*)d_out;                  // [32768,4,784]

    prep_w<<<(784 * 56 + 255) / 256, 256, 0, stream>>>(Wlin);
    prep_x<<<4096, 256, 0, stream>>>(x);

    dim3 grid(256 * 7);                          // 1792 blocks, same-XCD siblings
    dim3 block(512);
    patch_linear_mfma<<<grid, block, 0, stream>>>(blin, out);
}